// Round 1
// baseline (248.141 us; speedup 1.0000x reference)
//
#include <hip/hip_runtime.h>

#define LP 400
#define LQ 50
#define BZ 32
#define SZ 768
#define HH 128

__device__ __forceinline__ float fexp2(float x) {
#if __has_builtin(__builtin_amdgcn_exp2f)
  return __builtin_amdgcn_exp2f(x);
#else
  return exp2f(x);
#endif
}
__device__ __forceinline__ float frcp(float x) {
#if __has_builtin(__builtin_amdgcn_rcpf)
  return __builtin_amdgcn_rcpf(x);
#else
  return 1.0f / x;
#endif
}

// K0: Wvv[b][g] = Wv_b[g] + sum_h v[b][h] * Wv_w[g][h]   (einsum "bh,gh->bg")
__global__ __launch_bounds__(256) void wvv_kernel(
    const float* __restrict__ v, const float* __restrict__ Wv_w,
    const float* __restrict__ Wv_b, float* __restrict__ Wvv) {
  int id = blockIdx.x * 256 + threadIdx.x;  // 0..4095
  int b = id >> 7, g = id & 127;
  const float4* vb = reinterpret_cast<const float4*>(v + b * HH);
  const float4* wr = reinterpret_cast<const float4*>(Wv_w + g * HH);
  float s = Wv_b[g];
#pragma unroll
  for (int i = 0; i < HH / 4; ++i) {
    float4 a = vb[i], w = wr[i];
    s = fmaf(a.x, w.x, s); s = fmaf(a.y, w.y, s);
    s = fmaf(a.z, w.z, s); s = fmaf(a.w, w.w, s);
  }
  Wvv[id] = s;
}

// Generic: C[m][h] = scale * ( sum_s A[m][s]*W[h][s] + bias[h] + bias2[m&31][h] )
// M_tile = 16*TM, N_tile = 64 (grid.y selects h-half), K_tile = 64.
// 256 threads = 16 (tm) x 16 (th); thread owns m = mblk+tm+16i (i<TM), h = hbase+th+16j (j<4).
template <int TM>
__global__ __launch_bounds__(256) void gemm_bias(
    const float* __restrict__ A,      // [M, 768]
    const float* __restrict__ W,      // [128, 768]
    const float* __restrict__ bias,   // [128]
    const float* __restrict__ bias2,  // [32,128] or nullptr, row = m & 31
    float* __restrict__ C,            // [M, 128]
    float scale) {
  constexpr int MT = 16 * TM;
  __shared__ float As[MT][68];  // +4 pad: 68 % 32 = 4 -> adjacent rows 4 banks apart
  __shared__ float Ws[64][68];
  const int t = threadIdx.x;
  const int mblk = blockIdx.x * MT;
  const int hbase = blockIdx.y * 64;
  const int tm = t >> 4, th = t & 15;
  float acc[TM][4];
#pragma unroll
  for (int i = 0; i < TM; ++i)
#pragma unroll
    for (int j = 0; j < 4; ++j) acc[i][j] = 0.f;

  for (int k0 = 0; k0 < SZ; k0 += 64) {
#pragma unroll
    for (int i = 0; i < MT / 16; ++i) {  // A tile: MT x 64 floats, coalesced float4
      int f = t + i * 256;
      int row = f >> 4, c4 = (f & 15) << 2;
      *reinterpret_cast<float4*>(&As[row][c4]) =
          *reinterpret_cast<const float4*>(&A[(mblk + row) * SZ + k0 + c4]);
    }
#pragma unroll
    for (int i = 0; i < 4; ++i) {  // W tile: 64 x 64 floats
      int f = t + i * 256;
      int row = f >> 4, c4 = (f & 15) << 2;
      *reinterpret_cast<float4*>(&Ws[row][c4]) =
          *reinterpret_cast<const float4*>(&W[(hbase + row) * SZ + k0 + c4]);
    }
    __syncthreads();
#pragma unroll
    for (int kk = 0; kk < 16; ++kk) {
      float4 w[4];
#pragma unroll
      for (int j = 0; j < 4; ++j)
        w[j] = *reinterpret_cast<const float4*>(&Ws[th + 16 * j][kk * 4]);
#pragma unroll
      for (int i = 0; i < TM; ++i) {
        float4 a4 = *reinterpret_cast<const float4*>(&As[tm + 16 * i][kk * 4]);
#pragma unroll
        for (int j = 0; j < 4; ++j) {
          acc[i][j] = fmaf(a4.x, w[j].x, acc[i][j]);
          acc[i][j] = fmaf(a4.y, w[j].y, acc[i][j]);
          acc[i][j] = fmaf(a4.z, w[j].z, acc[i][j]);
          acc[i][j] = fmaf(a4.w, w[j].w, acc[i][j]);
        }
      }
    }
    __syncthreads();
  }
#pragma unroll
  for (int i = 0; i < TM; ++i) {
    int m = mblk + tm + 16 * i;
#pragma unroll
    for (int j = 0; j < 4; ++j) {
      int h = hbase + th + 16 * j;
      float r = acc[i][j] + bias[h];
      if (bias2) r += bias2[(m & 31) * HH + h];
      C[m * HH + h] = r * scale;
    }
  }
}

// K2: s[p,b,q] = sum_h v[b,h]*tanh(Wup'[p,b,h] + W2'[q,b,h]); softmax over q -> a.
// Inputs pre-scaled by 2*log2(e): tanh(y) = 1 - 2*rcp(exp2(y') + 1).
// Block = 256 (4 waves), each wave does 4 p's. Lane = qs(0..3) + 4*hs(0..15); lane owns 8 h.
// W2 for this b staged in LDS with per-row rotation (col4' = (col4+q)&31) -> <=2-way banks.
__global__ __launch_bounds__(256) void score_softmax(
    const float* __restrict__ Wup,  // [12800,128] pre-scaled
    const float* __restrict__ W2,   // [1600,128] pre-scaled (rows q*32+b)
    const float* __restrict__ v,    // [32,128] (unscaled)
    float* __restrict__ aw) {       // [12800,50]
  const int b = blockIdx.y;
  const int pbase = blockIdx.x * 16;
  const int t = threadIdx.x;
  const int wv = t >> 6, lane = t & 63;
  const int qs = lane & 3, hs = lane >> 2;
  const int h8 = hs * 8;

  __shared__ float W2s[LQ][HH];
  for (int f = t; f < LQ * (HH / 4); f += 256) {  // 1600 float4
    int q = f >> 5, c4 = f & 31;
    float4 val = *reinterpret_cast<const float4*>(&W2[(q * BZ + b) * HH + c4 * 4]);
    int cc = (c4 + q) & 31;  // rotate row q by q float4-slots
    *reinterpret_cast<float4*>(&W2s[q][cc * 4]) = val;
  }
  __syncthreads();

  float4 v0 = *reinterpret_cast<const float4*>(&v[b * HH + h8]);
  float4 v1 = *reinterpret_cast<const float4*>(&v[b * HH + h8 + 4]);
  const float sv8 = v0.x + v0.y + v0.z + v0.w + v1.x + v1.y + v1.z + v1.w;
  const int c40 = h8 >> 2;

  for (int pi = 0; pi < 4; ++pi) {
    const int p = pbase + wv * 4 + pi;
    const float* wr = &Wup[(p * BZ + b) * HH + h8];
    float4 u0 = *reinterpret_cast<const float4*>(wr);
    float4 u1 = *reinterpret_cast<const float4*>(wr + 4);
    float sq[13];
#pragma unroll
    for (int c = 0; c < 13; ++c) {
      int q = c * 4 + qs;
      float part = 0.f;
      if (q < LQ) {
        int ca = (c40 + q) & 31, cb = (c40 + 1 + q) & 31;
        float4 t0 = *reinterpret_cast<const float4*>(&W2s[q][ca * 4]);
        float4 t1 = *reinterpret_cast<const float4*>(&W2s[q][cb * 4]);
        float a2 = 0.f, r;
        r = frcp(fexp2(u0.x + t0.x) + 1.f); a2 = fmaf(v0.x, r, a2);
        r = frcp(fexp2(u0.y + t0.y) + 1.f); a2 = fmaf(v0.y, r, a2);
        r = frcp(fexp2(u0.z + t0.z) + 1.f); a2 = fmaf(v0.z, r, a2);
        r = frcp(fexp2(u0.w + t0.w) + 1.f); a2 = fmaf(v0.w, r, a2);
        r = frcp(fexp2(u1.x + t1.x) + 1.f); a2 = fmaf(v1.x, r, a2);
        r = frcp(fexp2(u1.y + t1.y) + 1.f); a2 = fmaf(v1.y, r, a2);
        r = frcp(fexp2(u1.z + t1.z) + 1.f); a2 = fmaf(v1.z, r, a2);
        r = frcp(fexp2(u1.w + t1.w) + 1.f); a2 = fmaf(v1.w, r, a2);
        part = sv8 - 2.f * a2;  // sum_h v*tanh over this lane's 8 h
      }
      // reduce over the 16 hs-lanes sharing this qs (lane bits 2..5)
      part += __shfl_xor(part, 4);
      part += __shfl_xor(part, 8);
      part += __shfl_xor(part, 16);
      part += __shfl_xor(part, 32);
      sq[c] = (q < LQ) ? part : -3.0e38f;
    }
    float m = sq[0];
#pragma unroll
    for (int c = 1; c < 13; ++c) m = fmaxf(m, sq[c]);
    m = fmaxf(m, __shfl_xor(m, 1));
    m = fmaxf(m, __shfl_xor(m, 2));
    float ssum = 0.f;
    float ev[13];
#pragma unroll
    for (int c = 0; c < 13; ++c) {
      float e = (c * 4 + qs < LQ) ? fexp2((sq[c] - m) * 1.4426950408889634f) : 0.f;
      ev[c] = e;
      ssum += e;
    }
    ssum += __shfl_xor(ssum, 1);
    ssum += __shfl_xor(ssum, 2);
    float rinv = frcp(ssum);  // ssum in [1, 50]
    if (hs == 0) {
#pragma unroll
      for (int c = 0; c < 13; ++c) {
        int q = c * 4 + qs;
        if (q < LQ) aw[(p * BZ + b) * LQ + q] = ev[c] * rinv;
      }
    }
  }
}

// K3: out[p,b,s] = sum_q a[p,b,q] * Uq[q,b,s].  Block: 192 thr (3 waves), one b,
// 16 p's, thread owns float4 of s. a staged in LDS, broadcast-read (conflict-free).
__global__ __launch_bounds__(192) void ctx_kernel(
    const float* __restrict__ aw,  // [12800,50]
    const float* __restrict__ Uq,  // [1600,768]
    float* __restrict__ out) {     // [12800,768]
  const int b = blockIdx.y;
  const int pbase = blockIdx.x * 16;
  const int t = threadIdx.x;
  __shared__ float as[16][52];
  for (int f = t; f < 16 * LQ; f += 192) {
    int row = f / LQ, col = f - row * LQ;
    as[row][col] = aw[((pbase + row) * BZ + b) * LQ + col];
  }
  __syncthreads();
  const int s4 = t * 4;
  float4 acc[16];
#pragma unroll
  for (int i = 0; i < 16; ++i) acc[i] = make_float4(0.f, 0.f, 0.f, 0.f);
#pragma unroll 2
  for (int q = 0; q < LQ; ++q) {
    float4 u = *reinterpret_cast<const float4*>(&Uq[(q * BZ + b) * SZ + s4]);
#pragma unroll
    for (int i = 0; i < 16; ++i) {
      float av = as[i][q];
      acc[i].x = fmaf(av, u.x, acc[i].x);
      acc[i].y = fmaf(av, u.y, acc[i].y);
      acc[i].z = fmaf(av, u.z, acc[i].z);
      acc[i].w = fmaf(av, u.w, acc[i].w);
    }
  }
#pragma unroll
  for (int i = 0; i < 16; ++i)
    *reinterpret_cast<float4*>(&out[((pbase + i) * BZ + b) * SZ + s4]) = acc[i];
}

extern "C" void kernel_launch(void* const* d_in, const int* in_sizes, int n_in,
                              void* d_out, int out_size, void* d_ws, size_t ws_size,
                              hipStream_t stream) {
  const float* Up   = (const float*)d_in[0];
  const float* Uq   = (const float*)d_in[1];
  const float* Wp_w = (const float*)d_in[2];
  const float* Wp_b = (const float*)d_in[3];
  const float* Wq_w = (const float*)d_in[4];
  const float* Wq_b = (const float*)d_in[5];
  const float* Wv_w = (const float*)d_in[6];
  const float* Wv_b = (const float*)d_in[7];
  const float* v    = (const float*)d_in[8];
  float* out = (float*)d_out;

  float* ws  = (float*)d_ws;
  float* Wvv = ws;                        // 32*128        = 4096
  float* W2  = Wvv + BZ * HH;             // 50*32*128     = 204800
  float* Wup = W2 + LQ * BZ * HH;         // 400*32*128    = 1638400
  float* aw  = Wup + LP * BZ * HH;        // 400*32*50     = 640000  (total ~9.5 MiB)

  const float TS = 2.8853900817779268f;  // 2*log2(e): folded so tanh needs 1 exp2 + 1 rcp

  wvv_kernel<<<dim3(16), dim3(256), 0, stream>>>(v, Wv_w, Wv_b, Wvv);
  gemm_bias<4><<<dim3(LP * BZ / 64, 2), dim3(256), 0, stream>>>(
      Up, Wp_w, Wp_b, nullptr, Wup, TS);
  gemm_bias<1><<<dim3(LQ * BZ / 16, 2), dim3(256), 0, stream>>>(
      Uq, Wq_w, Wq_b, Wvv, W2, TS);
  score_softmax<<<dim3(LP / 16, BZ), dim3(256), 0, stream>>>(Wup, W2, v, aw);
  ctx_kernel<<<dim3(LP / 16, BZ), dim3(192), 0, stream>>>(aw, Uq, out);
}

// Round 4
// 185.715 us; speedup vs baseline: 1.3361x; 1.3361x over previous
//
#include <hip/hip_runtime.h>

#define LP 400
#define LQ 50
#define BZ 32
#define SZ 768
#define HH 128
#define PROWS 14464  // 14400 real rows (12800 Up + 1600 Uq) padded to 113*128

typedef unsigned short u16;
typedef __attribute__((ext_vector_type(8))) short short8;
typedef __attribute__((ext_vector_type(4))) float f32x4;

__device__ __forceinline__ float fexp2(float x) {
#if __has_builtin(__builtin_amdgcn_exp2f)
  return __builtin_amdgcn_exp2f(x);
#else
  return exp2f(x);
#endif
}
__device__ __forceinline__ float frcp(float x) {
#if __has_builtin(__builtin_amdgcn_rcpf)
  return __builtin_amdgcn_rcpf(x);
#else
  return 1.0f / x;
#endif
}

// pack two f32's top-16-bits (truncated bf16) into one u32
__device__ __forceinline__ unsigned pack2(float x, float y) {
  return (__float_as_uint(x) >> 16) | (__float_as_uint(y) & 0xffff0000u);
}
// residual after truncating to bf16 (exact in f32)
__device__ __forceinline__ float remf(float x) {
  return x - __uint_as_float(__float_as_uint(x) & 0xffff0000u);
}

// K0: split Wp_w / Wq_w (each 128x768 f32) into hi/lo truncated-bf16 planes.
__global__ __launch_bounds__(256) void convw_kernel(
    const float* __restrict__ Wp_w, const float* __restrict__ Wq_w,
    u16* __restrict__ Wph, u16* __restrict__ Wpl,
    u16* __restrict__ Wqh, u16* __restrict__ Wql) {
  int gid = blockIdx.x * 256 + threadIdx.x;  // 0..24575
  int base = gid * 8;
  const float* src;
  u16 *dh, *dl;
  if (base < HH * SZ) {
    src = Wp_w + base; dh = Wph + base; dl = Wpl + base;
  } else {
    int o = base - HH * SZ;
    src = Wq_w + o; dh = Wqh + o; dl = Wql + o;
  }
  float4 x0 = *(const float4*)src;
  float4 x1 = *(const float4*)(src + 4);
  uint4 H, L;
  H.x = pack2(x0.x, x0.y); H.y = pack2(x0.z, x0.w);
  H.z = pack2(x1.x, x1.y); H.w = pack2(x1.z, x1.w);
  L.x = pack2(remf(x0.x), remf(x0.y)); L.y = pack2(remf(x0.z), remf(x0.w));
  L.z = pack2(remf(x1.x), remf(x1.y)); L.w = pack2(remf(x1.z), remf(x1.w));
  *(uint4*)dh = H;
  *(uint4*)dl = L;
}

// K1: Wvv[b][g] = Wv_b[g] + sum_h v[b][h] * Wv_w[g][h]
__global__ __launch_bounds__(256) void wvv_kernel(
    const float* __restrict__ v, const float* __restrict__ Wv_w,
    const float* __restrict__ Wv_b, float* __restrict__ Wvv) {
  int id = blockIdx.x * 256 + threadIdx.x;  // 0..4095
  int b = id >> 7, g = id & 127;
  const float4* vb = reinterpret_cast<const float4*>(v + b * HH);
  const float4* wr = reinterpret_cast<const float4*>(Wv_w + g * HH);
  float s = Wv_b[g];
#pragma unroll
  for (int i = 0; i < HH / 4; ++i) {
    float4 a = vb[i], w = wr[i];
    s = fmaf(a.x, w.x, s); s = fmaf(a.y, w.y, s);
    s = fmaf(a.z, w.z, s); s = fmaf(a.w, w.w, s);
  }
  Wvv[id] = s;
}

// K2: split-bf16 MFMA GEMM. Unified rows 0..14399 = [Up | Uq], N=128, K split in 2.
// Block: 256 thr (4 waves 2x2, wave tile 64x64), BM=128, BN=128, BK=32.
// partial[z][row][128] f32 (z = K-half) -> lives in d_out (scratch until ctx).
__global__ __launch_bounds__(256, 1) void mfma_gemm(
    const float* __restrict__ Up, const float* __restrict__ Uq,
    const u16* __restrict__ Wph, const u16* __restrict__ Wpl,
    const u16* __restrict__ Wqh, const u16* __restrict__ Wql,
    float* __restrict__ partial) {
  // stride 40 u16 = 80 B rows: frag reads & staging writes spread uniformly over banks
  __shared__ u16 Ah[128][40], Al[128][40], Bh[128][40], Bl[128][40];
  const int t = threadIdx.x, lane = t & 63, wid = t >> 6;
  const int bx = blockIdx.x, z = blockIdx.y;
  const int m0 = bx * 128;
  const bool probq = (bx >= 100);
  const u16* WH = probq ? Wqh : Wph;
  const u16* WL = probq ? Wql : Wpl;
  const int k0base = z * 384;

  const int ra = t >> 1, kh = (t & 1) * 16;  // staging: row, k-offset (16 elems)
  const int grow = m0 + ra;
  const float* srcA = nullptr;
  if (grow < 12800) srcA = Up + grow * SZ;
  else if (grow < 14400) srcA = Uq + (grow - 12800) * SZ;
  const u16* srcWH = WH + ra * SZ;
  const u16* srcWL = WL + ra * SZ;

  const int wm = (wid >> 1) * 64, wn = (wid & 1) * 64;
  const int fr = lane & 15, fg = lane >> 4;

  f32x4 acc[4][4];
#pragma unroll
  for (int i = 0; i < 4; ++i)
#pragma unroll
    for (int j = 0; j < 4; ++j) acc[i][j] = (f32x4){0.f, 0.f, 0.f, 0.f};

  float4 a0, a1, a2, a3;
  uint4 wh0, wh1, wl0, wl1;

#define GLOAD(s)                                                         \
  do {                                                                   \
    int kk = k0base + (s) * 32 + kh;                                     \
    if (srcA) {                                                          \
      a0 = *(const float4*)(srcA + kk);                                  \
      a1 = *(const float4*)(srcA + kk + 4);                              \
      a2 = *(const float4*)(srcA + kk + 8);                              \
      a3 = *(const float4*)(srcA + kk + 12);                             \
    } else {                                                             \
      a0 = a1 = a2 = a3 = make_float4(0.f, 0.f, 0.f, 0.f);               \
    }                                                                    \
    wh0 = *(const uint4*)(srcWH + kk); wh1 = *(const uint4*)(srcWH + kk + 8); \
    wl0 = *(const uint4*)(srcWL + kk); wl1 = *(const uint4*)(srcWL + kk + 8); \
  } while (0)

#define WSTORE()                                                          \
  do {                                                                    \
    uint4 H0, H1, L0, L1;                                                 \
    H0.x = pack2(a0.x, a0.y); H0.y = pack2(a0.z, a0.w);                   \
    H0.z = pack2(a1.x, a1.y); H0.w = pack2(a1.z, a1.w);                   \
    H1.x = pack2(a2.x, a2.y); H1.y = pack2(a2.z, a2.w);                   \
    H1.z = pack2(a3.x, a3.y); H1.w = pack2(a3.z, a3.w);                   \
    L0.x = pack2(remf(a0.x), remf(a0.y)); L0.y = pack2(remf(a0.z), remf(a0.w)); \
    L0.z = pack2(remf(a1.x), remf(a1.y)); L0.w = pack2(remf(a1.z), remf(a1.w)); \
    L1.x = pack2(remf(a2.x), remf(a2.y)); L1.y = pack2(remf(a2.z), remf(a2.w)); \
    L1.z = pack2(remf(a3.x), remf(a3.y)); L1.w = pack2(remf(a3.z), remf(a3.w)); \
    *(uint4*)&Ah[ra][kh] = H0; *(uint4*)&Ah[ra][kh + 8] = H1;             \
    *(uint4*)&Al[ra][kh] = L0; *(uint4*)&Al[ra][kh + 8] = L1;             \
    *(uint4*)&Bh[ra][kh] = wh0; *(uint4*)&Bh[ra][kh + 8] = wh1;           \
    *(uint4*)&Bl[ra][kh] = wl0; *(uint4*)&Bl[ra][kh + 8] = wl1;           \
  } while (0)

  GLOAD(0);
  WSTORE();
  __syncthreads();

  for (int s = 0; s < 12; ++s) {
    if (s < 11) GLOAD(s + 1);  // prefetch issued before MFMA: HBM latency hides (T14)
    short8 ah[4], al[4], bh[4], bl[4];
#pragma unroll
    for (int i = 0; i < 4; ++i) {
      ah[i] = *(const short8*)&Ah[wm + i * 16 + fr][fg * 8];
      al[i] = *(const short8*)&Al[wm + i * 16 + fr][fg * 8];
      bh[i] = *(const short8*)&Bh[wn + i * 16 + fr][fg * 8];
      bl[i] = *(const short8*)&Bl[wn + i * 16 + fr][fg * 8];
    }
#pragma unroll
    for (int i = 0; i < 4; ++i)
#pragma unroll
      for (int j = 0; j < 4; ++j) {
        acc[i][j] = __builtin_amdgcn_mfma_f32_16x16x32_bf16(ah[i], bh[j], acc[i][j], 0, 0, 0);
        acc[i][j] = __builtin_amdgcn_mfma_f32_16x16x32_bf16(ah[i], bl[j], acc[i][j], 0, 0, 0);
        acc[i][j] = __builtin_amdgcn_mfma_f32_16x16x32_bf16(al[i], bh[j], acc[i][j], 0, 0, 0);
      }
    __syncthreads();
    if (s < 11) WSTORE();
    __syncthreads();
  }
#undef GLOAD
#undef WSTORE

  float* pz = partial + (size_t)z * (PROWS * HH);
#pragma unroll
  for (int i = 0; i < 4; ++i) {
    int r0 = m0 + wm + i * 16 + fg * 4;
#pragma unroll
    for (int j = 0; j < 4; ++j) {
      int c = wn + j * 16 + fr;
#pragma unroll
      for (int e = 0; e < 4; ++e) pz[(r0 + e) * HH + c] = acc[i][j][e];
    }
  }
}

// K3: sum K-split partials + bias (+Wvv for Uq rows), *TS, scatter to Wup / W2 bufs.
__global__ __launch_bounds__(256) void reduce_kernel(
    const float* __restrict__ partial, const float* __restrict__ Wp_b,
    const float* __restrict__ Wq_b, const float* __restrict__ Wvv,
    float* __restrict__ WupB, float* __restrict__ W2B, float TS) {
  int idx = blockIdx.x * 256 + threadIdx.x;  // 0..460799 (14400*32 float4)
  int row = idx >> 5, h = (idx & 31) * 4;
  float4 p0 = *(const float4*)&partial[(size_t)row * HH + h];
  float4 p1 = *(const float4*)&partial[(size_t)(PROWS + row) * HH + h];
  float4 r;
  if (row < 12800) {
    float4 bb = *(const float4*)&Wp_b[h];
    r.x = (p0.x + p1.x + bb.x) * TS; r.y = (p0.y + p1.y + bb.y) * TS;
    r.z = (p0.z + p1.z + bb.z) * TS; r.w = (p0.w + p1.w + bb.w) * TS;
    *(float4*)&WupB[(size_t)row * HH + h] = r;
  } else {
    int rr = row - 12800, bz = rr & 31;
    float4 bb = *(const float4*)&Wq_b[h];
    float4 wv = *(const float4*)&Wvv[bz * HH + h];
    r.x = (p0.x + p1.x + bb.x + wv.x) * TS; r.y = (p0.y + p1.y + bb.y + wv.y) * TS;
    r.z = (p0.z + p1.z + bb.z + wv.z) * TS; r.w = (p0.w + p1.w + bb.w + wv.w) * TS;
    *(float4*)&W2B[(size_t)rr * HH + h] = r;
  }
}

// K4: q-per-lane score + softmax. s~[q] = -2 * sum_h v[h]*rcp(exp2(x')+1)
// (the sum_h v term is softmax-shift-invariant and dropped).
// Block: 256 thr, 4 waves x 4 p = 16 p, one b. W2s rows stride 129 -> lane-q reads 2-way (free).
__global__ __launch_bounds__(256) void score_softmax(
    const float* __restrict__ WupB, const float* __restrict__ W2B,
    const float* __restrict__ v, float* __restrict__ aw, float TS) {
  const int b = blockIdx.y, pbase = blockIdx.x * 16;
  const int t = threadIdx.x, lane = t & 63, w = t >> 6;
  __shared__ float W2s[LQ][129];
  __shared__ float Wps[16][HH];
  __shared__ float vsh[HH];

  for (int f = t; f < LQ * 32; f += 256) {
    int q = f >> 5, c4 = f & 31;
    float4 x = *(const float4*)&W2B[(size_t)(q * BZ + b) * HH + c4 * 4];
    W2s[q][c4 * 4 + 0] = x.x; W2s[q][c4 * 4 + 1] = x.y;
    W2s[q][c4 * 4 + 2] = x.z; W2s[q][c4 * 4 + 3] = x.w;
  }
  for (int f = t; f < 16 * 32; f += 256) {
    int i = f >> 5, c4 = f & 31;
    *(float4*)&Wps[i][c4 * 4] =
        *(const float4*)&WupB[(size_t)((pbase + i) * BZ + b) * HH + c4 * 4];
  }
  if (t < 32) *(float4*)&vsh[t * 4] = *(const float4*)&v[b * HH + t * 4];
  __syncthreads();

  const int q = (lane < LQ) ? lane : (LQ - 1);
  const int prow = w * 4;
  float A0 = 0.f, A1 = 0.f, A2 = 0.f, A3 = 0.f;
  for (int h = 0; h < HH; h += 4) {
#pragma unroll
    for (int j = 0; j < 4; ++j) {
      float w2 = W2s[q][h + j];
      float vj = vsh[h + j];
      float r0 = frcp(fexp2(Wps[prow + 0][h + j] + w2) + 1.f);
      float r1 = frcp(fexp2(Wps[prow + 1][h + j] + w2) + 1.f);
      float r2 = frcp(fexp2(Wps[prow + 2][h + j] + w2) + 1.f);
      float r3 = frcp(fexp2(Wps[prow + 3][h + j] + w2) + 1.f);
      A0 = fmaf(vj, r0, A0); A1 = fmaf(vj, r1, A1);
      A2 = fmaf(vj, r2, A2); A3 = fmaf(vj, r3, A3);
    }
  }

#define SOFTMAX(AR, PI)                                                   \
  do {                                                                    \
    float a = (lane < LQ) ? (AR) : 1e30f;                                 \
    float mn = a;                                                         \
    mn = fminf(mn, __shfl_xor(mn, 1));  mn = fminf(mn, __shfl_xor(mn, 2)); \
    mn = fminf(mn, __shfl_xor(mn, 4));  mn = fminf(mn, __shfl_xor(mn, 8)); \
    mn = fminf(mn, __shfl_xor(mn, 16)); mn = fminf(mn, __shfl_xor(mn, 32)); \
    float e = fexp2((mn - a) * TS); /* lanes>=50: exp2(-huge)=0 */        \
    float sm = e;                                                         \
    sm += __shfl_xor(sm, 1);  sm += __shfl_xor(sm, 2);                    \
    sm += __shfl_xor(sm, 4);  sm += __shfl_xor(sm, 8);                    \
    sm += __shfl_xor(sm, 16); sm += __shfl_xor(sm, 32);                   \
    float val = e * frcp(sm);                                             \
    if (lane < LQ)                                                        \
      aw[(size_t)((pbase + prow + (PI)) * BZ + b) * LQ + lane] = val;     \
  } while (0)

  SOFTMAX(A0, 0); SOFTMAX(A1, 1); SOFTMAX(A2, 2); SOFTMAX(A3, 3);
#undef SOFTMAX
}

// K5: out[p,b,s] = sum_q a[p,b,q] * Uq[q,b,s]. 25 p per block, 192 thr, thread owns float4 of s.
__global__ __launch_bounds__(192) void ctx_kernel(
    const float* __restrict__ aw, const float* __restrict__ Uq,
    float* __restrict__ out) {
  const int b = blockIdx.y;
  const int pbase = blockIdx.x * 25;
  const int t = threadIdx.x;
  __shared__ float as[25][LQ];
  for (int f = t; f < 25 * LQ; f += 192) {
    int i = f / LQ, qq = f - i * LQ;
    as[i][qq] = aw[(size_t)((pbase + i) * BZ + b) * LQ + qq];
  }
  __syncthreads();
  const int s4 = t * 4;
  f32x4 acc[25];
#pragma unroll
  for (int i = 0; i < 25; ++i) acc[i] = (f32x4){0.f, 0.f, 0.f, 0.f};
  for (int qp = 0; qp < LQ; qp += 2) {
    float4 u0 = *(const float4*)&Uq[(size_t)(qp * BZ + b) * SZ + s4];
    float4 u1 = *(const float4*)&Uq[(size_t)((qp + 1) * BZ + b) * SZ + s4];
#pragma unroll
    for (int i = 0; i < 25; ++i) {
      float2 a2 = *(const float2*)&as[i][qp];
      acc[i][0] = fmaf(a2.x, u0.x, acc[i][0]); acc[i][1] = fmaf(a2.x, u0.y, acc[i][1]);
      acc[i][2] = fmaf(a2.x, u0.z, acc[i][2]); acc[i][3] = fmaf(a2.x, u0.w, acc[i][3]);
      acc[i][0] = fmaf(a2.y, u1.x, acc[i][0]); acc[i][1] = fmaf(a2.y, u1.y, acc[i][1]);
      acc[i][2] = fmaf(a2.y, u1.z, acc[i][2]); acc[i][3] = fmaf(a2.y, u1.w, acc[i][3]);
    }
  }
#pragma unroll
  for (int i = 0; i < 25; ++i) {
    float4 r = make_float4(acc[i][0], acc[i][1], acc[i][2], acc[i][3]);
    *(float4*)&out[(size_t)((pbase + i) * BZ + b) * SZ + s4] = r;
  }
}

extern "C" void kernel_launch(void* const* d_in, const int* in_sizes, int n_in,
                              void* d_out, int out_size, void* d_ws, size_t ws_size,
                              hipStream_t stream) {
  const float* Up   = (const float*)d_in[0];
  const float* Uq   = (const float*)d_in[1];
  const float* Wp_w = (const float*)d_in[2];
  const float* Wp_b = (const float*)d_in[3];
  const float* Wq_w = (const float*)d_in[4];
  const float* Wq_b = (const float*)d_in[5];
  const float* Wv_w = (const float*)d_in[6];
  const float* Wv_b = (const float*)d_in[7];
  const float* v    = (const float*)d_in[8];
  float* out = (float*)d_out;

  // workspace: ~10.7 MB
  float* ws   = (float*)d_ws;
  float* Wvv  = ws;                       // 32*128        = 4096
  float* WupB = Wvv + BZ * HH;            // 12800*128     = 1638400
  float* W2B  = WupB + LP * BZ * HH;      // 1600*128      = 204800
  float* awB  = W2B + LQ * BZ * HH;       // 12800*50      = 640000
  u16* Wph = (u16*)(awB + LP * BZ * LQ);  // 4 x 98304 u16
  u16* Wpl = Wph + HH * SZ;
  u16* Wqh = Wpl + HH * SZ;
  u16* Wql = Wqh + HH * SZ;

  // K-split partials [2][14464][128] f32 = 14.8 MB live in d_out (39.3 MB),
  // which is scratch until ctx_kernel fully overwrites it at the end.
  float* partial = out;

  const float TS = 2.8853900817779268f;  // 2*log2(e)

  convw_kernel<<<dim3(96), dim3(256), 0, stream>>>(Wp_w, Wq_w, Wph, Wpl, Wqh, Wql);
  wvv_kernel<<<dim3(16), dim3(256), 0, stream>>>(v, Wv_w, Wv_b, Wvv);
  mfma_gemm<<<dim3(113, 2), dim3(256), 0, stream>>>(Up, Uq, Wph, Wpl, Wqh, Wql, partial);
  reduce_kernel<<<dim3(1800), dim3(256), 0, stream>>>(partial, Wp_b, Wq_b, Wvv, WupB, W2B, TS);
  score_softmax<<<dim3(LP / 16, BZ), dim3(256), 0, stream>>>(WupB, W2B, v, awB, TS);
  ctx_kernel<<<dim3(16, BZ), dim3(192), 0, stream>>>(awB, Uq, out);
}

// Round 6
// 175.421 us; speedup vs baseline: 1.4145x; 1.0587x over previous
//
#include <hip/hip_runtime.h>

#define LP 400
#define LQ 50
#define BZ 32
#define SZ 768
#define HH 128
#define PROWS 14464  // 14400 real rows (12800 Up + 1600 Uq) padded to 113*128

typedef unsigned short u16;
typedef __attribute__((ext_vector_type(8))) short short8;
typedef __attribute__((ext_vector_type(4))) float f32x4;

__device__ __forceinline__ float fexp2(float x) {
#if __has_builtin(__builtin_amdgcn_exp2f)
  return __builtin_amdgcn_exp2f(x);
#else
  return exp2f(x);
#endif
}
__device__ __forceinline__ float frcp(float x) {
#if __has_builtin(__builtin_amdgcn_rcpf)
  return __builtin_amdgcn_rcpf(x);
#else
  return 1.0f / x;
#endif
}

// pack two f32's top-16-bits (truncated bf16) into one u32
__device__ __forceinline__ unsigned pack2(float x, float y) {
  return (__float_as_uint(x) >> 16) | (__float_as_uint(y) & 0xffff0000u);
}
// residual after truncating to bf16 (exact in f32)
__device__ __forceinline__ float remf(float x) {
  return x - __uint_as_float(__float_as_uint(x) & 0xffff0000u);
}

// K0: fused prep. Blocks 0..95: split Wp_w/Wq_w into hi/lo bf16 planes.
//     Blocks 96..111: Wvv[b][g] = Wv_b[g] + sum_h v[b][h]*Wv_w[g][h].
__global__ __launch_bounds__(256) void prep_kernel(
    const float* __restrict__ Wp_w, const float* __restrict__ Wq_w,
    const float* __restrict__ v, const float* __restrict__ Wv_w,
    const float* __restrict__ Wv_b,
    u16* __restrict__ Wph, u16* __restrict__ Wpl,
    u16* __restrict__ Wqh, u16* __restrict__ Wql, float* __restrict__ Wvv) {
  const int bx = blockIdx.x, t = threadIdx.x;
  if (bx < 96) {
    int gid = bx * 256 + t;  // 0..24575
    int base = gid * 8;
    const float* src;
    u16 *dh, *dl;
    if (base < HH * SZ) {
      src = Wp_w + base; dh = Wph + base; dl = Wpl + base;
    } else {
      int o = base - HH * SZ;
      src = Wq_w + o; dh = Wqh + o; dl = Wql + o;
    }
    float4 x0 = *(const float4*)src;
    float4 x1 = *(const float4*)(src + 4);
    uint4 H, L;
    H.x = pack2(x0.x, x0.y); H.y = pack2(x0.z, x0.w);
    H.z = pack2(x1.x, x1.y); H.w = pack2(x1.z, x1.w);
    L.x = pack2(remf(x0.x), remf(x0.y)); L.y = pack2(remf(x0.z), remf(x0.w));
    L.z = pack2(remf(x1.x), remf(x1.y)); L.w = pack2(remf(x1.z), remf(x1.w));
    *(uint4*)dh = H;
    *(uint4*)dl = L;
  } else {
    int id = (bx - 96) * 256 + t;  // 0..4095
    int b = id >> 7, g = id & 127;
    const float4* vb = reinterpret_cast<const float4*>(v + b * HH);
    const float4* wr = reinterpret_cast<const float4*>(Wv_w + g * HH);
    float s = Wv_b[g];
#pragma unroll
    for (int i = 0; i < HH / 4; ++i) {
      float4 a = vb[i], w = wr[i];
      s = fmaf(a.x, w.x, s); s = fmaf(a.y, w.y, s);
      s = fmaf(a.z, w.z, s); s = fmaf(a.w, w.w, s);
    }
    Wvv[id] = s;
  }
}

// K1: split-bf16 MFMA GEMM. Unified rows 0..14399 = [Up | Uq], N=128, K split in 2.
// Block: 256 thr (4 waves 2x2, wave tile 64x64), BM=128, BN=128, BK=32.
// partial[z][row][128] f32 (z = K-half) in d_ws.
__global__ __launch_bounds__(256, 1) void mfma_gemm(
    const float* __restrict__ Up, const float* __restrict__ Uq,
    const u16* __restrict__ Wph, const u16* __restrict__ Wpl,
    const u16* __restrict__ Wqh, const u16* __restrict__ Wql,
    float* __restrict__ partial) {
  // stride 40 u16 = 80 B rows: frag reads & staging writes spread uniformly over banks
  __shared__ u16 Ah[128][40], Al[128][40], Bh[128][40], Bl[128][40];
  const int t = threadIdx.x, lane = t & 63, wid = t >> 6;
  const int bx = blockIdx.x, z = blockIdx.y;
  const int m0 = bx * 128;
  const bool probq = (bx >= 100);
  const u16* WH = probq ? Wqh : Wph;
  const u16* WL = probq ? Wql : Wpl;
  const int k0base = z * 384;

  const int ra = t >> 1, kh = (t & 1) * 16;  // staging: row, k-offset (16 elems)
  const int grow = m0 + ra;
  const float* srcA = nullptr;
  if (grow < 12800) srcA = Up + grow * SZ;
  else if (grow < 14400) srcA = Uq + (grow - 12800) * SZ;
  const u16* srcWH = WH + ra * SZ;
  const u16* srcWL = WL + ra * SZ;

  const int wm = (wid >> 1) * 64, wn = (wid & 1) * 64;
  const int fr = lane & 15, fg = lane >> 4;

  f32x4 acc[4][4];
#pragma unroll
  for (int i = 0; i < 4; ++i)
#pragma unroll
    for (int j = 0; j < 4; ++j) acc[i][j] = (f32x4){0.f, 0.f, 0.f, 0.f};

  float4 a0, a1, a2, a3;
  uint4 wh0, wh1, wl0, wl1;

#define GLOAD(s)                                                         \
  do {                                                                   \
    int kk = k0base + (s) * 32 + kh;                                     \
    if (srcA) {                                                          \
      a0 = *(const float4*)(srcA + kk);                                  \
      a1 = *(const float4*)(srcA + kk + 4);                              \
      a2 = *(const float4*)(srcA + kk + 8);                              \
      a3 = *(const float4*)(srcA + kk + 12);                             \
    } else {                                                             \
      a0 = a1 = a2 = a3 = make_float4(0.f, 0.f, 0.f, 0.f);               \
    }                                                                    \
    wh0 = *(const uint4*)(srcWH + kk); wh1 = *(const uint4*)(srcWH + kk + 8); \
    wl0 = *(const uint4*)(srcWL + kk); wl1 = *(const uint4*)(srcWL + kk + 8); \
  } while (0)

#define WSTORE()                                                          \
  do {                                                                    \
    uint4 H0, H1, L0, L1;                                                 \
    H0.x = pack2(a0.x, a0.y); H0.y = pack2(a0.z, a0.w);                   \
    H0.z = pack2(a1.x, a1.y); H0.w = pack2(a1.z, a1.w);                   \
    H1.x = pack2(a2.x, a2.y); H1.y = pack2(a2.z, a2.w);                   \
    H1.z = pack2(a3.x, a3.y); H1.w = pack2(a3.z, a3.w);                   \
    L0.x = pack2(remf(a0.x), remf(a0.y)); L0.y = pack2(remf(a0.z), remf(a0.w)); \
    L0.z = pack2(remf(a1.x), remf(a1.y)); L0.w = pack2(remf(a1.z), remf(a1.w)); \
    L1.x = pack2(remf(a2.x), remf(a2.y)); L1.y = pack2(remf(a2.z), remf(a2.w)); \
    L1.z = pack2(remf(a3.x), remf(a3.y)); L1.w = pack2(remf(a3.z), remf(a3.w)); \
    *(uint4*)&Ah[ra][kh] = H0; *(uint4*)&Ah[ra][kh + 8] = H1;             \
    *(uint4*)&Al[ra][kh] = L0; *(uint4*)&Al[ra][kh + 8] = L1;             \
    *(uint4*)&Bh[ra][kh] = wh0; *(uint4*)&Bh[ra][kh + 8] = wh1;           \
    *(uint4*)&Bl[ra][kh] = wl0; *(uint4*)&Bl[ra][kh + 8] = wl1;           \
  } while (0)

  GLOAD(0);
  WSTORE();
  __syncthreads();

  for (int s = 0; s < 12; ++s) {
    if (s < 11) GLOAD(s + 1);  // prefetch issued before MFMA: HBM latency hides (T14)
    short8 ah[4], al[4], bh[4], bl[4];
#pragma unroll
    for (int i = 0; i < 4; ++i) {
      ah[i] = *(const short8*)&Ah[wm + i * 16 + fr][fg * 8];
      al[i] = *(const short8*)&Al[wm + i * 16 + fr][fg * 8];
      bh[i] = *(const short8*)&Bh[wn + i * 16 + fr][fg * 8];
      bl[i] = *(const short8*)&Bl[wn + i * 16 + fr][fg * 8];
    }
#pragma unroll
    for (int i = 0; i < 4; ++i)
#pragma unroll
      for (int j = 0; j < 4; ++j) {
        acc[i][j] = __builtin_amdgcn_mfma_f32_16x16x32_bf16(ah[i], bh[j], acc[i][j], 0, 0, 0);
        acc[i][j] = __builtin_amdgcn_mfma_f32_16x16x32_bf16(ah[i], bl[j], acc[i][j], 0, 0, 0);
        acc[i][j] = __builtin_amdgcn_mfma_f32_16x16x32_bf16(al[i], bh[j], acc[i][j], 0, 0, 0);
      }
    __syncthreads();
    if (s < 11) WSTORE();
    __syncthreads();
  }
#undef GLOAD
#undef WSTORE

  float* pz = partial + (size_t)z * (PROWS * HH);
#pragma unroll
  for (int i = 0; i < 4; ++i) {
    int r0 = m0 + wm + i * 16 + fg * 4;
#pragma unroll
    for (int j = 0; j < 4; ++j) {
      int c = wn + j * 16 + fr;
#pragma unroll
      for (int e = 0; e < 4; ++e) pz[(r0 + e) * HH + c] = acc[i][j][e];
    }
  }
}

// K2: tiny reduce of the 1600 Uq-projection rows only:
// W2B[rr][h] = (p0+p1+Wq_b[h]+Wvv[b][h])*TS, rr = q*32+b.
__global__ __launch_bounds__(256) void w2prep_kernel(
    const float* __restrict__ partial, const float* __restrict__ Wq_b,
    const float* __restrict__ Wvv, float* __restrict__ W2B, float TS) {
  int idx = blockIdx.x * 256 + threadIdx.x;  // 0..51199 (1600 rows x 32 float4)
  int rr = idx >> 5, h = (idx & 31) * 4;
  int row = 12800 + rr, b = rr & 31;
  float4 p0 = *(const float4*)&partial[(size_t)row * HH + h];
  float4 p1 = *(const float4*)&partial[(size_t)(PROWS + row) * HH + h];
  float4 bb = *(const float4*)&Wq_b[h];
  float4 wv = *(const float4*)&Wvv[b * HH + h];
  float4 r;
  r.x = (p0.x + p1.x + bb.x + wv.x) * TS;
  r.y = (p0.y + p1.y + bb.y + wv.y) * TS;
  r.z = (p0.z + p1.z + bb.z + wv.z) * TS;
  r.w = (p0.w + p1.w + bb.w + wv.w) * TS;
  *(float4*)&W2B[(size_t)rr * HH + h] = r;
}

// K3: fused score + softmax + context. One block = 16 p x 1 b.
// Phase 1 (256 thr): Wps staged from the two K-split partials (+bias,*TS);
//   s~[q] = -2*sum_h v[h]*rcp(exp2(x')+1) per-lane-q; softmax -> as[16][52] in LDS.
// Phase 2 (192 thr): out[p,b,s] = sum_q as[p][q]*Uq[q,b,s], float4 per thread.
// XCD swizzle: b = (f%8)*4 + (f/8)%4 pins each b's Uq slice (153 KB) to one XCD L2.
__global__ __launch_bounds__(256) void score_ctx(
    const float* __restrict__ partial, const float* __restrict__ Wp_b,
    const float* __restrict__ W2B, const float* __restrict__ v,
    const float* __restrict__ Uq, float* __restrict__ out, float TS) {
  const int f = blockIdx.x;  // 0..799
  const int b = (f & 7) * 4 + ((f >> 3) & 3);
  const int pbase = (f >> 5) * 16;
  const int t = threadIdx.x, lane = t & 63, w = t >> 6;
  __shared__ float W2s[LQ][129];
  __shared__ float Wps[16][HH];
  __shared__ float vsh[HH];
  __shared__ float as[16][52];

  for (int ff = t; ff < LQ * 32; ff += 256) {
    int q = ff >> 5, c4 = ff & 31;
    float4 x = *(const float4*)&W2B[(size_t)(q * BZ + b) * HH + c4 * 4];
    W2s[q][c4 * 4 + 0] = x.x; W2s[q][c4 * 4 + 1] = x.y;
    W2s[q][c4 * 4 + 2] = x.z; W2s[q][c4 * 4 + 3] = x.w;
  }
  for (int ff = t; ff < 16 * 32; ff += 256) {  // Wup reduce folded in
    int i = ff >> 5, c4 = ff & 31;
    int grow = (pbase + i) * BZ + b;
    float4 p0 = *(const float4*)&partial[(size_t)grow * HH + c4 * 4];
    float4 p1 = *(const float4*)&partial[(size_t)(PROWS + grow) * HH + c4 * 4];
    float4 bb = *(const float4*)&Wp_b[c4 * 4];
    float4 r;
    r.x = (p0.x + p1.x + bb.x) * TS; r.y = (p0.y + p1.y + bb.y) * TS;
    r.z = (p0.z + p1.z + bb.z) * TS; r.w = (p0.w + p1.w + bb.w) * TS;
    *(float4*)&Wps[i][c4 * 4] = r;
  }
  if (t < 32) *(float4*)&vsh[t * 4] = *(const float4*)&v[b * HH + t * 4];
  __syncthreads();

  const int q = (lane < LQ) ? lane : (LQ - 1);
  const int prow = w * 4;
  float A0 = 0.f, A1 = 0.f, A2 = 0.f, A3 = 0.f;
  for (int h = 0; h < HH; h += 4) {
#pragma unroll
    for (int j = 0; j < 4; ++j) {
      float w2 = W2s[q][h + j];
      float vj = vsh[h + j];
      float r0 = frcp(fexp2(Wps[prow + 0][h + j] + w2) + 1.f);
      float r1 = frcp(fexp2(Wps[prow + 1][h + j] + w2) + 1.f);
      float r2 = frcp(fexp2(Wps[prow + 2][h + j] + w2) + 1.f);
      float r3 = frcp(fexp2(Wps[prow + 3][h + j] + w2) + 1.f);
      A0 = fmaf(vj, r0, A0); A1 = fmaf(vj, r1, A1);
      A2 = fmaf(vj, r2, A2); A3 = fmaf(vj, r3, A3);
    }
  }

#define SOFTMAX(AR, PI)                                                   \
  do {                                                                    \
    float a = (lane < LQ) ? (AR) : 1e30f;                                 \
    float mn = a;                                                         \
    mn = fminf(mn, __shfl_xor(mn, 1));  mn = fminf(mn, __shfl_xor(mn, 2)); \
    mn = fminf(mn, __shfl_xor(mn, 4));  mn = fminf(mn, __shfl_xor(mn, 8)); \
    mn = fminf(mn, __shfl_xor(mn, 16)); mn = fminf(mn, __shfl_xor(mn, 32)); \
    float e = fexp2((mn - a) * TS); /* lanes>=50: exp2(-huge)=0 */        \
    float sm = e;                                                         \
    sm += __shfl_xor(sm, 1);  sm += __shfl_xor(sm, 2);                    \
    sm += __shfl_xor(sm, 4);  sm += __shfl_xor(sm, 8);                    \
    sm += __shfl_xor(sm, 16); sm += __shfl_xor(sm, 32);                   \
    float val = e * frcp(sm);                                             \
    if (lane < LQ) as[prow + (PI)][lane] = val;                           \
  } while (0)

  SOFTMAX(A0, 0); SOFTMAX(A1, 1); SOFTMAX(A2, 2); SOFTMAX(A3, 3);
#undef SOFTMAX
  __syncthreads();

  if (t < 192) {
    const int s4 = t * 4;
    f32x4 acc[16];
#pragma unroll
    for (int i = 0; i < 16; ++i) acc[i] = (f32x4){0.f, 0.f, 0.f, 0.f};
    for (int qp = 0; qp < LQ; qp += 2) {
      float4 u0 = *(const float4*)&Uq[(size_t)(qp * BZ + b) * SZ + s4];
      float4 u1 = *(const float4*)&Uq[(size_t)((qp + 1) * BZ + b) * SZ + s4];
#pragma unroll
      for (int i = 0; i < 16; ++i) {
        float2 a2 = *(const float2*)&as[i][qp];
        acc[i][0] = fmaf(a2.x, u0.x, acc[i][0]); acc[i][1] = fmaf(a2.x, u0.y, acc[i][1]);
        acc[i][2] = fmaf(a2.x, u0.z, acc[i][2]); acc[i][3] = fmaf(a2.x, u0.w, acc[i][3]);
        acc[i][0] = fmaf(a2.y, u1.x, acc[i][0]); acc[i][1] = fmaf(a2.y, u1.y, acc[i][1]);
        acc[i][2] = fmaf(a2.y, u1.z, acc[i][2]); acc[i][3] = fmaf(a2.y, u1.w, acc[i][3]);
      }
    }
#pragma unroll
    for (int i = 0; i < 16; ++i) {
      float4 r = make_float4(acc[i][0], acc[i][1], acc[i][2], acc[i][3]);
      *(float4*)&out[(size_t)((pbase + i) * BZ + b) * SZ + s4] = r;
    }
  }
}

extern "C" void kernel_launch(void* const* d_in, const int* in_sizes, int n_in,
                              void* d_out, int out_size, void* d_ws, size_t ws_size,
                              hipStream_t stream) {
  const float* Up   = (const float*)d_in[0];
  const float* Uq   = (const float*)d_in[1];
  const float* Wp_w = (const float*)d_in[2];
  const float* Wp_b = (const float*)d_in[3];
  const float* Wq_w = (const float*)d_in[4];
  const float* Wq_b = (const float*)d_in[5];
  const float* Wv_w = (const float*)d_in[6];
  const float* Wv_b = (const float*)d_in[7];
  const float* v    = (const float*)d_in[8];
  float* out = (float*)d_out;

  // workspace: ~16.4 MB (partials must NOT live in d_out: score_ctx reads them
  // while other blocks write out).
  float* ws      = (float*)d_ws;
  float* Wvv     = ws;                        // 32*128   = 4096 f
  float* W2B     = Wvv + BZ * HH;             // 1600*128 = 204800 f
  u16* Wph       = (u16*)(W2B + LQ * BZ * HH);
  u16* Wpl       = Wph + HH * SZ;             // 4 planes x 98304 u16
  u16* Wqh       = Wpl + HH * SZ;
  u16* Wql       = Wqh + HH * SZ;
  float* partial = (float*)(Wql + HH * SZ);   // 2*PROWS*128 f = 14.8 MB

  const float TS = 2.8853900817779268f;  // 2*log2(e)

  prep_kernel<<<dim3(112), dim3(256), 0, stream>>>(
      Wp_w, Wq_w, v, Wv_w, Wv_b, Wph, Wpl, Wqh, Wql, Wvv);
  mfma_gemm<<<dim3(113, 2), dim3(256), 0, stream>>>(
      Up, Uq, Wph, Wpl, Wqh, Wql, partial);
  w2prep_kernel<<<dim3(200), dim3(256), 0, stream>>>(partial, Wq_b, Wvv, W2B, TS);
  score_ctx<<<dim3(800), dim3(256), 0, stream>>>(
      partial, Wp_b, W2B, v, Uq, out, TS);
}

// Round 7
// 174.250 us; speedup vs baseline: 1.4241x; 1.0067x over previous
//
#include <hip/hip_runtime.h>

#define LP 400
#define LQ 50
#define BZ 32
#define SZ 768
#define HH 128
#define PR_TOT 14400  // 12800 Up rows + 1600 Uq rows; 225 blocks x 64 = exact

typedef unsigned short u16;
typedef __attribute__((ext_vector_type(8))) short short8;
typedef __attribute__((ext_vector_type(4))) float f32x4;

__device__ __forceinline__ float fexp2(float x) {
#if __has_builtin(__builtin_amdgcn_exp2f)
  return __builtin_amdgcn_exp2f(x);
#else
  return exp2f(x);
#endif
}
__device__ __forceinline__ float frcp(float x) {
#if __has_builtin(__builtin_amdgcn_rcpf)
  return __builtin_amdgcn_rcpf(x);
#else
  return 1.0f / x;
#endif
}

// pack two f32's top-16-bits (truncated bf16) into one u32
__device__ __forceinline__ unsigned pack2(float x, float y) {
  return (__float_as_uint(x) >> 16) | (__float_as_uint(y) & 0xffff0000u);
}
// residual after truncating to bf16 (exact in f32)
__device__ __forceinline__ float remf(float x) {
  return x - __uint_as_float(__float_as_uint(x) & 0xffff0000u);
}

// K0: fused prep. Blocks 0..95: split Wp_w/Wq_w into hi/lo bf16 planes.
//     Blocks 96..111: Wvv[b][g] = Wv_b[g] + sum_h v[b][h]*Wv_w[g][h].
__global__ __launch_bounds__(256) void prep_kernel(
    const float* __restrict__ Wp_w, const float* __restrict__ Wq_w,
    const float* __restrict__ v, const float* __restrict__ Wv_w,
    const float* __restrict__ Wv_b,
    u16* __restrict__ Wph, u16* __restrict__ Wpl,
    u16* __restrict__ Wqh, u16* __restrict__ Wql, float* __restrict__ Wvv) {
  const int bx = blockIdx.x, t = threadIdx.x;
  if (bx < 96) {
    int gid = bx * 256 + t;  // 0..24575
    int base = gid * 8;
    const float* src;
    u16 *dh, *dl;
    if (base < HH * SZ) {
      src = Wp_w + base; dh = Wph + base; dl = Wpl + base;
    } else {
      int o = base - HH * SZ;
      src = Wq_w + o; dh = Wqh + o; dl = Wql + o;
    }
    float4 x0 = *(const float4*)src;
    float4 x1 = *(const float4*)(src + 4);
    uint4 H, L;
    H.x = pack2(x0.x, x0.y); H.y = pack2(x0.z, x0.w);
    H.z = pack2(x1.x, x1.y); H.w = pack2(x1.z, x1.w);
    L.x = pack2(remf(x0.x), remf(x0.y)); L.y = pack2(remf(x0.z), remf(x0.w));
    L.z = pack2(remf(x1.x), remf(x1.y)); L.w = pack2(remf(x1.z), remf(x1.w));
    *(uint4*)dh = H;
    *(uint4*)dl = L;
  } else {
    int id = (bx - 96) * 256 + t;  // 0..4095
    int b = id >> 7, g = id & 127;
    const float4* vb = reinterpret_cast<const float4*>(v + b * HH);
    const float4* wr = reinterpret_cast<const float4*>(Wv_w + g * HH);
    float s = Wv_b[g];
#pragma unroll
    for (int i = 0; i < HH / 4; ++i) {
      float4 a = vb[i], w = wr[i];
      s = fmaf(a.x, w.x, s); s = fmaf(a.y, w.y, s);
      s = fmaf(a.z, w.z, s); s = fmaf(a.w, w.w, s);
    }
    Wvv[id] = s;
  }
}

// K1: split-bf16 MFMA GEMM. Rows 0..14399 = [Up | Uq], N=128, K split in 2 (z).
// BM=64: grid (225, 2) = 450 blocks (~1.8/CU, 5 fit by LDS) vs 226 before.
// 4 waves 2x2, wave tile 32x64. Waves 0,1 stage A; all stage W (wave-uniform).
__global__ __launch_bounds__(256, 2) void mfma_gemm(
    const float* __restrict__ Up, const float* __restrict__ Uq,
    const u16* __restrict__ Wph, const u16* __restrict__ Wpl,
    const u16* __restrict__ Wqh, const u16* __restrict__ Wql,
    float* __restrict__ partial) {
  // stride 40 u16 = 80 B rows: frag reads & staging writes spread uniformly over banks
  __shared__ u16 Ah[64][40], Al[64][40], Bh[128][40], Bl[128][40];
  const int t = threadIdx.x, lane = t & 63, wid = t >> 6;
  const int bx = blockIdx.x, z = blockIdx.y;
  const int m0 = bx * 64;
  const bool probq = (bx >= 200);  // 12800/64
  const u16* WH = probq ? Wqh : Wph;
  const u16* WL = probq ? Wql : Wpl;
  const int k0base = z * 384;

  const int ra = t >> 1, kh = (t & 1) * 16;  // staging: row, k-offset (16 elems)
  const bool hasA = (ra < 64);               // wave-uniform: waves 0,1
  const int grow = m0 + (ra & 63);
  const float* srcA = (grow < 12800) ? (Up + (size_t)grow * SZ)
                                     : (Uq + (size_t)(grow - 12800) * SZ);
  const u16* srcWH = WH + ra * SZ;
  const u16* srcWL = WL + ra * SZ;

  const int wm = (wid >> 1) * 32, wn = (wid & 1) * 64;
  const int fr = lane & 15, fg = lane >> 4;

  f32x4 acc[2][4];
#pragma unroll
  for (int i = 0; i < 2; ++i)
#pragma unroll
    for (int j = 0; j < 4; ++j) acc[i][j] = (f32x4){0.f, 0.f, 0.f, 0.f};

  float4 a0, a1, a2, a3;
  uint4 wh0, wh1, wl0, wl1;

#define GLOAD(s)                                                         \
  do {                                                                   \
    int kk = k0base + (s) * 32 + kh;                                     \
    if (hasA) {                                                          \
      a0 = *(const float4*)(srcA + kk);                                  \
      a1 = *(const float4*)(srcA + kk + 4);                              \
      a2 = *(const float4*)(srcA + kk + 8);                              \
      a3 = *(const float4*)(srcA + kk + 12);                             \
    }                                                                    \
    wh0 = *(const uint4*)(srcWH + kk); wh1 = *(const uint4*)(srcWH + kk + 8); \
    wl0 = *(const uint4*)(srcWL + kk); wl1 = *(const uint4*)(srcWL + kk + 8); \
  } while (0)

#define WSTORE()                                                          \
  do {                                                                    \
    if (hasA) {                                                           \
      uint4 H0, H1, L0, L1;                                               \
      H0.x = pack2(a0.x, a0.y); H0.y = pack2(a0.z, a0.w);                 \
      H0.z = pack2(a1.x, a1.y); H0.w = pack2(a1.z, a1.w);                 \
      H1.x = pack2(a2.x, a2.y); H1.y = pack2(a2.z, a2.w);                 \
      H1.z = pack2(a3.x, a3.y); H1.w = pack2(a3.z, a3.w);                 \
      L0.x = pack2(remf(a0.x), remf(a0.y)); L0.y = pack2(remf(a0.z), remf(a0.w)); \
      L0.z = pack2(remf(a1.x), remf(a1.y)); L0.w = pack2(remf(a1.z), remf(a1.w)); \
      L1.x = pack2(remf(a2.x), remf(a2.y)); L1.y = pack2(remf(a2.z), remf(a2.w)); \
      L1.z = pack2(remf(a3.x), remf(a3.y)); L1.w = pack2(remf(a3.z), remf(a3.w)); \
      *(uint4*)&Ah[ra][kh] = H0; *(uint4*)&Ah[ra][kh + 8] = H1;           \
      *(uint4*)&Al[ra][kh] = L0; *(uint4*)&Al[ra][kh + 8] = L1;           \
    }                                                                     \
    *(uint4*)&Bh[ra][kh] = wh0; *(uint4*)&Bh[ra][kh + 8] = wh1;           \
    *(uint4*)&Bl[ra][kh] = wl0; *(uint4*)&Bl[ra][kh + 8] = wl1;           \
  } while (0)

  GLOAD(0);
  WSTORE();
  __syncthreads();

  for (int s = 0; s < 12; ++s) {
    if (s < 11) GLOAD(s + 1);  // prefetch issued before MFMA: HBM latency hides (T14)
    short8 ah[2], al[2], bh[4], bl[4];
#pragma unroll
    for (int i = 0; i < 2; ++i) {
      ah[i] = *(const short8*)&Ah[wm + i * 16 + fr][fg * 8];
      al[i] = *(const short8*)&Al[wm + i * 16 + fr][fg * 8];
    }
#pragma unroll
    for (int j = 0; j < 4; ++j) {
      bh[j] = *(const short8*)&Bh[wn + j * 16 + fr][fg * 8];
      bl[j] = *(const short8*)&Bl[wn + j * 16 + fr][fg * 8];
    }
#pragma unroll
    for (int i = 0; i < 2; ++i)
#pragma unroll
      for (int j = 0; j < 4; ++j) {
        acc[i][j] = __builtin_amdgcn_mfma_f32_16x16x32_bf16(ah[i], bh[j], acc[i][j], 0, 0, 0);
        acc[i][j] = __builtin_amdgcn_mfma_f32_16x16x32_bf16(ah[i], bl[j], acc[i][j], 0, 0, 0);
        acc[i][j] = __builtin_amdgcn_mfma_f32_16x16x32_bf16(al[i], bh[j], acc[i][j], 0, 0, 0);
      }
    __syncthreads();
    if (s < 11) WSTORE();
    __syncthreads();
  }
#undef GLOAD
#undef WSTORE

  float* pz = partial + (size_t)z * (PR_TOT * HH);
#pragma unroll
  for (int i = 0; i < 2; ++i) {
    int r0 = m0 + wm + i * 16 + fg * 4;
#pragma unroll
    for (int j = 0; j < 4; ++j) {
      int c = wn + j * 16 + fr;
#pragma unroll
      for (int e = 0; e < 4; ++e) pz[(size_t)(r0 + e) * HH + c] = acc[i][j][e];
    }
  }
}

// K2: fused score + softmax + context. One block = 8 p x 1 b; 1600 blocks.
// Staging folds BOTH K-split reductions (+bias,*TS): Wps (8 Up rows) and the
// full W2 (50 Uq rows, stored transposed W2s[h][q] -> lane-q reads stride-1).
// Phase 1: 4 waves x 2 p, lane = q: s~[q] = -2*sum_h v[h]*rcp(exp2(x')+1)
//   (the +sum_h v term is softmax-shift-invariant and dropped); softmax via shfl.
// Phase 2: 192 thr, thread owns float4 of s: out = sum_q as[p][q]*Uq[q,b,s].
// XCD swizzle: b = (f%8)*4 + (f/8)%4 pins each b's working set to one XCD L2.
__global__ __launch_bounds__(256, 4) void score_ctx(
    const float* __restrict__ partial, const float* __restrict__ Wp_b,
    const float* __restrict__ Wq_b, const float* __restrict__ Wvv,
    const float* __restrict__ v, const float* __restrict__ Uq,
    float* __restrict__ out, float TS) {
  const int f = blockIdx.x;  // 0..1599
  const int b = ((f & 7) << 2) | ((f >> 3) & 3);
  const int pbase = (f >> 5) * 8;
  const int t = threadIdx.x, lane = t & 63, w = t >> 6;
  __shared__ float W2s[HH][52];   // transposed: [h][q], pad 52
  __shared__ f32x4 Wps4[8][32];   // [p][h4]
  __shared__ f32x4 vsh4[32];
  __shared__ float as_[8][52];

  // W2 inline reduce -> transposed LDS (scalar writes, lane-stride-1: conflict-free)
  for (int ff = t; ff < LQ * 32; ff += 256) {
    int q_ = ff % LQ, c4 = ff / LQ;
    size_t row = 12800 + (size_t)(q_ * BZ + b);
    float4 p0 = *(const float4*)&partial[row * HH + c4 * 4];
    float4 p1 = *(const float4*)&partial[((size_t)PR_TOT + row) * HH + c4 * 4];
    float4 bb = *(const float4*)&Wq_b[c4 * 4];
    float4 wv = *(const float4*)&Wvv[b * HH + c4 * 4];
    W2s[c4 * 4 + 0][q_] = (p0.x + p1.x + bb.x + wv.x) * TS;
    W2s[c4 * 4 + 1][q_] = (p0.y + p1.y + bb.y + wv.y) * TS;
    W2s[c4 * 4 + 2][q_] = (p0.z + p1.z + bb.z + wv.z) * TS;
    W2s[c4 * 4 + 3][q_] = (p0.w + p1.w + bb.w + wv.w) * TS;
  }
  {  // Wps: 8 rows x 32 float4 = 256 slots = 1/thread
    int i = t >> 5, c4 = t & 31;
    size_t grow = (size_t)(pbase + i) * BZ + b;
    float4 p0 = *(const float4*)&partial[grow * HH + c4 * 4];
    float4 p1 = *(const float4*)&partial[((size_t)PR_TOT + grow) * HH + c4 * 4];
    float4 bb = *(const float4*)&Wp_b[c4 * 4];
    Wps4[i][c4] = (f32x4){(p0.x + p1.x + bb.x) * TS, (p0.y + p1.y + bb.y) * TS,
                          (p0.z + p1.z + bb.z) * TS, (p0.w + p1.w + bb.w) * TS};
  }
  if (t < 32) {
    float4 x = *(const float4*)&v[b * HH + t * 4];
    vsh4[t] = (f32x4){x.x, x.y, x.z, x.w};
  }
  __syncthreads();

  const int q = (lane < LQ) ? lane : (LQ - 1);
  const int prow = w * 2;
  float A0 = 0.f, A1 = 0.f;
  for (int h4 = 0; h4 < 32; ++h4) {
    f32x4 vj = vsh4[h4];
    f32x4 w0 = Wps4[prow][h4];      // broadcast b128
    f32x4 w1 = Wps4[prow + 1][h4];  // broadcast b128
    float s0 = W2s[h4 * 4 + 0][q];  // stride-1 in lane: conflict-free
    float s1 = W2s[h4 * 4 + 1][q];
    float s2 = W2s[h4 * 4 + 2][q];
    float s3 = W2s[h4 * 4 + 3][q];
    A0 = fmaf(vj[0], frcp(fexp2(w0[0] + s0) + 1.f), A0);
    A0 = fmaf(vj[1], frcp(fexp2(w0[1] + s1) + 1.f), A0);
    A0 = fmaf(vj[2], frcp(fexp2(w0[2] + s2) + 1.f), A0);
    A0 = fmaf(vj[3], frcp(fexp2(w0[3] + s3) + 1.f), A0);
    A1 = fmaf(vj[0], frcp(fexp2(w1[0] + s0) + 1.f), A1);
    A1 = fmaf(vj[1], frcp(fexp2(w1[1] + s1) + 1.f), A1);
    A1 = fmaf(vj[2], frcp(fexp2(w1[2] + s2) + 1.f), A1);
    A1 = fmaf(vj[3], frcp(fexp2(w1[3] + s3) + 1.f), A1);
  }

#define SOFTMAX(AR, PI)                                                   \
  do {                                                                    \
    float a = (lane < LQ) ? (AR) : 1e30f;                                 \
    float mn = a;                                                         \
    mn = fminf(mn, __shfl_xor(mn, 1));  mn = fminf(mn, __shfl_xor(mn, 2)); \
    mn = fminf(mn, __shfl_xor(mn, 4));  mn = fminf(mn, __shfl_xor(mn, 8)); \
    mn = fminf(mn, __shfl_xor(mn, 16)); mn = fminf(mn, __shfl_xor(mn, 32)); \
    float e = fexp2((mn - a) * TS); /* lanes>=50: exp2(-huge)=0 */        \
    float sm = e;                                                         \
    sm += __shfl_xor(sm, 1);  sm += __shfl_xor(sm, 2);                    \
    sm += __shfl_xor(sm, 4);  sm += __shfl_xor(sm, 8);                    \
    sm += __shfl_xor(sm, 16); sm += __shfl_xor(sm, 32);                   \
    float val = e * frcp(sm);                                             \
    if (lane < LQ) as_[prow + (PI)][lane] = val;                          \
  } while (0)

  SOFTMAX(A0, 0); SOFTMAX(A1, 1);
#undef SOFTMAX
  __syncthreads();

  if (t < 192) {
    const int s4 = t * 4;
    f32x4 acc[8];
#pragma unroll
    for (int i = 0; i < 8; ++i) acc[i] = (f32x4){0.f, 0.f, 0.f, 0.f};
    for (int qp = 0; qp < LQ; qp += 2) {
      float4 u0 = *(const float4*)&Uq[(size_t)(qp * BZ + b) * SZ + s4];
      float4 u1 = *(const float4*)&Uq[(size_t)((qp + 1) * BZ + b) * SZ + s4];
#pragma unroll
      for (int i = 0; i < 8; ++i) {
        float2 a2 = *(const float2*)&as_[i][qp];
        acc[i][0] = fmaf(a2.x, u0.x, acc[i][0]); acc[i][1] = fmaf(a2.x, u0.y, acc[i][1]);
        acc[i][2] = fmaf(a2.x, u0.z, acc[i][2]); acc[i][3] = fmaf(a2.x, u0.w, acc[i][3]);
        acc[i][0] = fmaf(a2.y, u1.x, acc[i][0]); acc[i][1] = fmaf(a2.y, u1.y, acc[i][1]);
        acc[i][2] = fmaf(a2.y, u1.z, acc[i][2]); acc[i][3] = fmaf(a2.y, u1.w, acc[i][3]);
      }
    }
#pragma unroll
    for (int i = 0; i < 8; ++i) {
      float4 r = make_float4(acc[i][0], acc[i][1], acc[i][2], acc[i][3]);
      *(float4*)&out[(size_t)((pbase + i) * BZ + b) * SZ + s4] = r;
    }
  }
}

extern "C" void kernel_launch(void* const* d_in, const int* in_sizes, int n_in,
                              void* d_out, int out_size, void* d_ws, size_t ws_size,
                              hipStream_t stream) {
  const float* Up   = (const float*)d_in[0];
  const float* Uq   = (const float*)d_in[1];
  const float* Wp_w = (const float*)d_in[2];
  const float* Wp_b = (const float*)d_in[3];
  const float* Wq_w = (const float*)d_in[4];
  const float* Wq_b = (const float*)d_in[5];
  const float* Wv_w = (const float*)d_in[6];
  const float* Wv_b = (const float*)d_in[7];
  const float* v    = (const float*)d_in[8];
  float* out = (float*)d_out;

  // workspace ~15.6 MB (partials must NOT live in d_out: score_ctx reads them
  // while other blocks write out).
  float* ws      = (float*)d_ws;
  float* Wvv     = ws;                        // 32*128 = 4096 f
  u16* Wph       = (u16*)(Wvv + BZ * HH);     // 4 planes x 98304 u16
  u16* Wpl       = Wph + HH * SZ;
  u16* Wqh       = Wpl + HH * SZ;
  u16* Wql       = Wqh + HH * SZ;
  float* partial = (float*)(Wql + HH * SZ);   // 2 x 14400 x 128 f = 14.75 MB

  const float TS = 2.8853900817779268f;  // 2*log2(e)

  prep_kernel<<<dim3(112), dim3(256), 0, stream>>>(
      Wp_w, Wq_w, v, Wv_w, Wv_b, Wph, Wpl, Wqh, Wql, Wvv);
  mfma_gemm<<<dim3(225, 2), dim3(256), 0, stream>>>(
      Up, Uq, Wph, Wpl, Wqh, Wql, partial);
  score_ctx<<<dim3(1600), dim3(256), 0, stream>>>(
      partial, Wp_b, Wq_b, Wvv, v, Uq, out, TS);
}